// Round 11
// baseline (1030.088 us; speedup 1.0000x reference)
//
#include <hip/hip_runtime.h>

typedef __attribute__((ext_vector_type(8))) _Float16 f16x8;
typedef __attribute__((ext_vector_type(4))) _Float16 f16x4;
typedef __attribute__((ext_vector_type(4))) float f32x4;

namespace {

constexpr int H_ = 64;
constexpr int R_ = 32;
constexpr int B_ = 64;
constexpr int C_ = 256;
constexpr int T_ = 512;
constexpr int N_ = B_ * C_;   // 16384 sequences

constexpr float NLOG2E  = -1.44269504088896f;
constexpr float N2LOG2E = -2.88539008177793f;

#define MFMA16(a, b, c) __builtin_amdgcn_mfma_f32_16x16x32_f16((a), (b), (c), 0, 0, 0)

// fused GRU combine with t_n = e^{-2 pn}, t_z = e^{-pz}:
// h' = [tn*(h - tz) + (h + tz)] / [(1+tn)(1+tz)]   -- 5 VALU + 1 rcp
__device__ __forceinline__ float gru_combine(float h, float t_n, float t_z) {
    float tz1 = 1.0f + t_z;
    float num = __fmaf_rn(t_n, h - t_z, h + t_z);
    float den = __fmaf_rn(t_n, tz1, tz1);
    return num * __builtin_amdgcn_rcpf(den);
}

// ---------------------------------------------------------------------------
// Pack GRU weights into fragment-linear fp16, prescaled:
//   r/z rows x NLOG2E  (so exp2 args come straight out of the MFMA)
//   n   rows x N2LOG2E
//  f0-1 : Whh0 r     f2-3 : Whh0 z     f4-5 : Whh0 n
//  f6-7 : Wih1 r     f8-9 : Whh1 r
//  f10-11: Wih1 z    f12-13: Whh1 z
//  f14-15: Wih1 n    f16-17: Whh1 n
// packed[((w*18 + f)*512) + lane*8 + j], k = (f&1)*32 + (lane>>4)*8 + j,
// out-row = hb + (lane&15) (+gate offset). Same (lane,j)->k map as the
// h-fragments, so the pack serves the A-operand role unchanged.
// ---------------------------------------------------------------------------
__global__ void pack_weights_kernel(const float* __restrict__ Whh0,
                                    const float* __restrict__ Wih1,
                                    const float* __restrict__ Whh1,
                                    _Float16* __restrict__ packed)
{
    const int b = blockIdx.x;          // 0..71
    const int w = b / 18, f = b % 18;
    const int l = threadIdx.x;         // 0..63
    const int c = l & 15, g = l >> 4;
    const int hb = w * 16;
    const int kk = f & 1;
    const float* src = Whh0;
    int row = 0;
    float scale = NLOG2E;
    switch (f >> 1) {
        case 0: src = Whh0; row = hb + c;        break;
        case 1: src = Whh0; row = 64 + hb + c;   break;
        case 2: src = Whh0; row = 128 + hb + c;  scale = N2LOG2E; break;
        case 3: src = Wih1; row = hb + c;        break;
        case 4: src = Whh1; row = hb + c;        break;
        case 5: src = Wih1; row = 64 + hb + c;   break;
        case 6: src = Whh1; row = 64 + hb + c;   break;
        case 7: src = Wih1; row = 128 + hb + c;  scale = N2LOG2E; break;
        case 8: src = Whh1; row = 128 + hb + c;  scale = N2LOG2E; break;
    }
    _Float16* dst = packed + ((size_t)(w * 18 + f) * 512) + (size_t)l * 8;
    #pragma unroll
    for (int j = 0; j < 8; ++j) {
        int k = kk * 32 + g * 8 + j;
        dst[j] = (_Float16)(src[row * 64 + k] * scale);
    }
}

// ---------------------------------------------------------------------------
// Layer-specialized MFMA GRU scan, transposed MFMA orientation.
// D = W (A-operand, register-resident) x h^T (B-operand, from LDS):
//   D col = lane&15 = seq, D row = (lane>>4)*4 + q = local hid.
// Each lane owns 4 CONSECUTIVE hid at one seq -> h-state writeback is a
// single ds_write_b64; x is one scalar per lane; hT epilogue is b128.
// Block = 16 sequences, 8 waves: waves 0-3 L0, waves 4-7 L1 (hid-slice w&3).
// One barrier per phase; xs double-buffered; setprio around MFMA clusters.
// All gate biases live in the MFMA C-operand (prescaled); r/z preacts come
// out of the MFMA ready for exp2.
// ---------------------------------------------------------------------------

#define PHASE_L0(PP, XB, DT)                                                  \
  do {                                                                        \
    const _Float16* h0rd = &h0s[(PP) ^ 1][0][0];                              \
    f16x8 a00 = *(const f16x8*)(h0rd + c * 72 + g * 8);                       \
    f16x8 a01 = *(const f16x8*)(h0rd + c * 72 + 32 + g * 8);                  \
    __builtin_amdgcn_s_setprio(1);                                            \
    f32x4 accr = MFMA16(Br[1], a01, MFMA16(Br[0], a00, vcb0r));               \
    f32x4 accz = MFMA16(Br[3], a01, MFMA16(Br[2], a00, vcb0z));               \
    f32x4 accn = MFMA16(Br[5], a01, MFMA16(Br[4], a00, vb0nh));               \
    __builtin_amdgcn_s_setprio(0);                                            \
    float xv = xs_[XB][DT][c];                                                \
    f16x4 hv;                                                                 \
    _Pragma("unroll")                                                         \
    for (int q = 0; q < 4; ++q) {                                             \
      float tr = __builtin_amdgcn_exp2f(__fmaf_rn(xv, wr0n[q], accr[q]));     \
      float r  = __builtin_amdgcn_rcpf(1.0f + tr);                            \
      float tz = __builtin_amdgcn_exp2f(__fmaf_rn(xv, wz0n[q], accz[q]));     \
      float tn = __builtin_amdgcn_exp2f(                                      \
          __fmaf_rn(r, accn[q], __fmaf_rn(xv, wn0s[q], b0nxs[q])));           \
      float hn = gru_combine(h0st[q], tn, tz);                                \
      h0st[q] = hn;                                                           \
      hv[q] = (_Float16)hn;                                                   \
    }                                                                         \
    *(f16x4*)&h0s[PP][c][hb4] = hv;                                           \
  } while (0)

#define PHASE_L1(PP, DOSTORE)                                                 \
  do {                                                                        \
    const _Float16* h0rd = &h0s[(PP) ^ 1][0][0];                              \
    const _Float16* h1rd = &h1s[(PP) ^ 1][0][0];                              \
    f16x8 a00 = *(const f16x8*)(h0rd + c * 72 + g * 8);                       \
    f16x8 a01 = *(const f16x8*)(h0rd + c * 72 + 32 + g * 8);                  \
    f16x8 ah0 = *(const f16x8*)(h1rd + c * 72 + g * 8);                       \
    f16x8 ah1 = *(const f16x8*)(h1rd + c * 72 + 32 + g * 8);                  \
    __builtin_amdgcn_s_setprio(1);                                            \
    f32x4 r1  = MFMA16(Br[3], ah1, MFMA16(Br[2], ah0,                         \
                MFMA16(Br[1], a01, MFMA16(Br[0], a00, vcb1r))));              \
    f32x4 z1  = MFMA16(Br[7], ah1, MFMA16(Br[6], ah0,                         \
                MFMA16(Br[5], a01, MFMA16(Br[4], a00, vcb1z))));              \
    f32x4 xn1 = MFMA16(Br[9],  a01, MFMA16(Br[8],  a00, vb1nx));              \
    f32x4 hn1 = MFMA16(Br[11], ah1, MFMA16(Br[10], ah0, vb1nh));              \
    __builtin_amdgcn_s_setprio(0);                                            \
    f16x4 hv;                                                                 \
    _Pragma("unroll")                                                         \
    for (int q = 0; q < 4; ++q) {                                             \
      float tr = __builtin_amdgcn_exp2f(r1[q]);                               \
      float r  = __builtin_amdgcn_rcpf(1.0f + tr);                            \
      float tz = __builtin_amdgcn_exp2f(z1[q]);                               \
      float tn = __builtin_amdgcn_exp2f(__fmaf_rn(r, hn1[q], xn1[q]));        \
      float hn = gru_combine(h1st[q], tn, tz);                                \
      h1st[q] = hn;                                                           \
      hv[q] = (_Float16)hn;                                                   \
    }                                                                         \
    if (DOSTORE) *(f16x4*)&h1s[PP][c][hb4] = hv;                              \
  } while (0)

__global__ __launch_bounds__(512, 4)
void gru_mfma_kernel(const float* __restrict__ x,
                     const _Float16* __restrict__ packedW,
                     const float* __restrict__ Wih0,
                     const float* __restrict__ bih0,
                     const float* __restrict__ bhh0,
                     const float* __restrict__ bih1,
                     const float* __restrict__ bhh1,
                     float* __restrict__ hT_out)
{
    __shared__ __align__(16) _Float16 h0s[2][16][72];   // row stride 144 B
    __shared__ __align__(16) _Float16 h1s[2][16][72];
    __shared__ __align__(16) float xs_[2][32][20];      // double-buffered tiles

    const int tid = threadIdx.x;
    const int l = tid & 63;
    const int w = tid >> 6;          // 0..7
    const bool isL0 = (w < 4);
    const int sl = w & 3;            // hid-slice 0..3
    const int c = l & 15, g = (l >> 4) & 3;
    const int hb = sl * 16;
    const int hb4 = hb + g * 4;      // this lane's 4-hid base
    const int n0 = blockIdx.x * 16;

    // resident weight A-fragments: L0 waves 6 frags, L1 waves 12 frags
    f16x8 Br[12];
    {
        const f16x8* bp = (const f16x8*)(packedW + (size_t)sl * 18 * 512);
        if (isL0) {
            #pragma unroll
            for (int f = 0; f < 6; ++f) Br[f] = bp[f * 64 + l];
        } else {
            #pragma unroll
            for (int f = 0; f < 12; ++f) Br[f] = bp[(6 + f) * 64 + l];
        }
    }

    // per-lane constants, now PER-q (hid = hb4 + q) vectors
    f32x4 wr0n = {0,0,0,0}, wz0n = {0,0,0,0}, wn0s = {0,0,0,0}, b0nxs = {0,0,0,0};
    f32x4 vcb0r = {0,0,0,0}, vcb0z = {0,0,0,0}, vb0nh = {0,0,0,0};
    f32x4 vcb1r = {0,0,0,0}, vcb1z = {0,0,0,0}, vb1nx = {0,0,0,0}, vb1nh = {0,0,0,0};
    #pragma unroll
    for (int q = 0; q < 4; ++q) {
        int hq = hb4 + q;
        if (isL0) {
            wr0n[q]  = NLOG2E  * Wih0[hq];
            wz0n[q]  = NLOG2E  * Wih0[64 + hq];
            wn0s[q]  = N2LOG2E * Wih0[128 + hq];
            b0nxs[q] = N2LOG2E * bih0[128 + hq];
            vcb0r[q] = NLOG2E  * (bhh0[hq] + bih0[hq]);
            vcb0z[q] = NLOG2E  * (bhh0[64 + hq] + bih0[64 + hq]);
            vb0nh[q] = N2LOG2E * bhh0[128 + hq];
        } else {
            vcb1r[q] = NLOG2E  * (bih1[hq] + bhh1[hq]);
            vcb1z[q] = NLOG2E  * (bih1[64 + hq] + bhh1[64 + hq]);
            vb1nx[q] = N2LOG2E * bih1[128 + hq];
            vb1nh[q] = N2LOG2E * bhh1[128 + hq];
        }
    }

    for (int p = tid; p < 2 * 16 * 72; p += 512) {
        (&h0s[0][0][0])[p] = (_Float16)0.0f;
        (&h1s[0][0][0])[p] = (_Float16)0.0f;
    }
    float h0st[4] = {0.f, 0.f, 0.f, 0.f};
    float h1st[4] = {0.f, 0.f, 0.f, 0.f};

    auto stage_x = [&](int t0) {
        int buf = (t0 >> 5) & 1;
        int tb = tid & 31;          // timestep within tile
        int ss = tid >> 5;          // 0..15 sequence
        xs_[buf][tb][ss] = x[(size_t)(n0 + ss) * T_ + t0 + tb];
    };

    // prologue: phase 0 (L0 only), parity 0, buffer 0
    stage_x(0);
    __syncthreads();
    if (isL0) PHASE_L0(0, 0, 0);

    // main loop: phases 1..510 in parity-static pairs (odd, even).
    for (int p = 1; p < T_ - 1; p += 2) {
        __syncthreads();
        if (isL0) PHASE_L0(1, (p >> 5) & 1, p & 31); else PHASE_L1(1, true);
        if ((p & 31) == 31) stage_x(p + 1);
        __syncthreads();
        if (isL0) PHASE_L0(0, ((p + 1) >> 5) & 1, (p + 1) & 31);
        else      PHASE_L1(0, true);
    }

    // leftover phase 511 (parity 1, buffer 1, row 31)
    __syncthreads();
    if (isL0) PHASE_L0(1, 1, 31); else PHASE_L1(1, true);

    // epilogue: phase 512 (L1 only), parity 0
    __syncthreads();
    if (!isL0) {
        PHASE_L1(0, false);
        float4 o;
        o.x = h1st[0]; o.y = h1st[1]; o.z = h1st[2]; o.w = h1st[3];
        *(float4*)&hT_out[(size_t)(n0 + c) * H_ + hb4] = o;
    }
}

// ---------------------------------------------------------------------------
// Heads: mu, softplus(d), v (R=32), resid = y - mu. One thread per sequence.
// ---------------------------------------------------------------------------
__global__ __launch_bounds__(256)
void heads_kernel(const float* __restrict__ hT,
                  const float* __restrict__ y,
                  const float* __restrict__ Wm, const float* __restrict__ bm,
                  const float* __restrict__ Wd, const float* __restrict__ bd,
                  const float* __restrict__ Wv, const float* __restrict__ bv,
                  float* __restrict__ v_out,
                  float* __restrict__ dd_out,
                  float* __restrict__ r_out)
{
    const int n = blockIdx.x * 256 + threadIdx.x;
    const float* h = hT + (size_t)n * H_;

    float hreg[H_];
    #pragma unroll
    for (int j = 0; j < H_; j += 4) {
        float4 q = *(const float4*)(h + j);
        hreg[j] = q.x; hreg[j + 1] = q.y; hreg[j + 2] = q.z; hreg[j + 3] = q.w;
    }
    float mu = bm[0], dv = bd[0];
    #pragma unroll
    for (int j = 0; j < H_; ++j) {
        mu = __fmaf_rn(Wm[j], hreg[j], mu);
        dv = __fmaf_rn(Wd[j], hreg[j], dv);
    }
    r_out[n]  = y[n] - mu;
    dd_out[n] = log1pf(__expf(dv));   // softplus

    for (int k = 0; k < R_; ++k) {
        float acc = bv[k];
        #pragma unroll
        for (int j = 0; j < H_; ++j)
            acc = __fmaf_rn(Wv[k * H_ + j], hreg[j], acc);
        v_out[(size_t)n * R_ + k] = acc;
    }
}

__device__ __forceinline__ float block_reduce_sum256(float* red, int tid, float val)
{
    red[tid] = val;
    __syncthreads();
    for (int off = 128; off > 0; off >>= 1) {
        if (tid < off) red[tid] += red[tid + off];
        __syncthreads();
    }
    float r = red[0];
    __syncthreads();
    return r;
}

// ---------------------------------------------------------------------------
// Per-batch Woodbury: sigma = V V^T + D.
// quad  = r^T D^-1 r - u^T M^-1 u,  u = V^T D^-1 r,  M = I + V^T D^-1 V
// logdet= sum log d + logdet M  (32x32 Cholesky)
// ---------------------------------------------------------------------------
__global__ __launch_bounds__(256)
void woodbury_kernel(const float* __restrict__ v_in,
                     const float* __restrict__ dd_in,
                     const float* __restrict__ r_in,
                     float* __restrict__ batch_out)
{
    __shared__ float Vl[C_][R_ + 1];
    __shared__ float Vw[C_][R_ + 1];
    __shared__ float wi[C_];
    __shared__ float rl[C_];
    __shared__ float red[256];
    __shared__ float MA[R_][R_ + 1];
    __shared__ float uA[R_], yA[R_], wA[R_];

    const int tid = threadIdx.x;
    const int nb  = blockIdx.x * C_;

    for (int p = tid; p < C_ * R_; p += 256) {
        int cc = p >> 5, k = p & 31;
        Vl[cc][k] = v_in[(size_t)(nb + cc) * R_ + k];
    }
    float dval = dd_in[nb + tid];
    float winv = 1.0f / dval;
    float rv   = r_in[nb + tid];
    wi[tid] = winv;
    rl[tid] = rv;
    __syncthreads();

    for (int p = tid; p < C_ * R_; p += 256) {
        int cc = p >> 5, k = p & 31;
        Vw[cc][k] = Vl[cc][k] * wi[cc];
    }
    __syncthreads();

    float slogd = block_reduce_sum256(red, tid, __logf(dval));
    float rDr   = block_reduce_sum256(red, tid, rv * rv * winv);

    #pragma unroll
    for (int e = 0; e < 4; ++e) {
        int p = tid + e * 256;
        int i = p >> 5, j = p & 31;
        float acc = (i == j) ? 1.0f : 0.0f;
        for (int cc = 0; cc < C_; ++cc)
            acc = __fmaf_rn(Vw[cc][i], Vl[cc][j], acc);
        MA[i][j] = acc;
    }
    if (tid < R_) {
        float acc = 0.0f;
        for (int cc = 0; cc < C_; ++cc)
            acc = __fmaf_rn(Vw[cc][tid], rl[cc], acc);
        uA[tid] = acc;
    }
    __syncthreads();

    for (int k = 0; k < R_; ++k) {
        if (tid == 0) MA[k][k] = sqrtf(MA[k][k]);
        __syncthreads();
        if (tid > k && tid < R_) MA[tid][k] /= MA[k][k];
        __syncthreads();
        if (tid > k && tid < R_) {
            float ljk = MA[tid][k];
            for (int i2 = k + 1; i2 <= tid; ++i2)
                MA[tid][i2] -= ljk * MA[i2][k];
        }
        __syncthreads();
    }
    float ldm = block_reduce_sum256(red, tid,
                    (tid < R_) ? 2.0f * __logf(MA[tid][tid]) : 0.0f);

    if (tid == 0) {
        for (int k = 0; k < R_; ++k) {
            float sv = uA[k];
            for (int i2 = 0; i2 < k; ++i2) sv -= MA[k][i2] * yA[i2];
            yA[k] = sv / MA[k][k];
        }
        for (int k = R_ - 1; k >= 0; --k) {
            float sv = yA[k];
            for (int i2 = k + 1; i2 < R_; ++i2) sv -= MA[i2][k] * wA[i2];
            wA[k] = sv / MA[k][k];
        }
        float uw = 0.0f;
        for (int k = 0; k < R_; ++k) uw += wA[k] * uA[k];
        batch_out[blockIdx.x] = (rDr - uw) + slogd + ldm;
    }
}

__global__ void finalize_kernel(const float* __restrict__ bws, float* __restrict__ out)
{
    float v = bws[threadIdx.x];
    #pragma unroll
    for (int off = 32; off > 0; off >>= 1)
        v += __shfl_down(v, off, 64);
    if (threadIdx.x == 0) out[0] = v * (1.0f / 64.0f);
}

} // anonymous namespace

extern "C" void kernel_launch(void* const* d_in, const int* in_sizes, int n_in,
                              void* d_out, int out_size, void* d_ws, size_t ws_size,
                              hipStream_t stream)
{
    const float* x    = (const float*)d_in[0];
    const float* y    = (const float*)d_in[1];
    const float* Wih0 = (const float*)d_in[2];
    const float* Whh0 = (const float*)d_in[3];
    const float* bih0 = (const float*)d_in[4];
    const float* bhh0 = (const float*)d_in[5];
    const float* Wih1 = (const float*)d_in[6];
    const float* Whh1 = (const float*)d_in[7];
    const float* bih1 = (const float*)d_in[8];
    const float* bhh1 = (const float*)d_in[9];
    const float* Wm   = (const float*)d_in[10];
    const float* bm   = (const float*)d_in[11];
    const float* Wd   = (const float*)d_in[12];
    const float* bd   = (const float*)d_in[13];
    const float* Wv   = (const float*)d_in[14];
    const float* bv   = (const float*)d_in[15];

    char* ws = (char*)d_ws;
    float*    hT     = (float*)(ws + 0);                 // N*64 f32   (4 MB)
    float*    v_ws   = (float*)(ws + 4194304);           // N*32 f32   (2 MB)
    float*    dd_ws  = (float*)(ws + 6291456);           // N f32
    float*    r_ws   = (float*)(ws + 6356992);           // N f32
    float*    b_ws   = (float*)(ws + 6422528);           // B f32
    _Float16* packed = (_Float16*)(ws + 6423552);        // 4*18*512 fp16 (73728 B)

    pack_weights_kernel<<<72, 64, 0, stream>>>(Whh0, Wih1, Whh1, packed);
    gru_mfma_kernel<<<N_ / 16, 512, 0, stream>>>(
        x, packed, Wih0, bih0, bhh0, bih1, bhh1, hT);
    heads_kernel<<<N_ / 256, 256, 0, stream>>>(
        hT, y, Wm, bm, Wd, bd, Wv, bv, v_ws, dd_ws, r_ws);
    woodbury_kernel<<<B_, 256, 0, stream>>>(v_ws, dd_ws, r_ws, b_ws);
    finalize_kernel<<<1, 64, 0, stream>>>(b_ws, (float*)d_out);
}

// Round 12
// 897.383 us; speedup vs baseline: 1.1479x; 1.1479x over previous
//
#include <hip/hip_runtime.h>

typedef __attribute__((ext_vector_type(8))) _Float16 f16x8;
typedef __attribute__((ext_vector_type(4))) float f32x4;

namespace {

constexpr int H_ = 64;
constexpr int R_ = 32;
constexpr int B_ = 64;
constexpr int C_ = 256;
constexpr int T_ = 512;
constexpr int N_ = B_ * C_;   // 16384 sequences

constexpr float NLOG2E  = -1.44269504088896f;
constexpr float N2LOG2E = -2.88539008177793f;

#define MFMA16(a, b, c) __builtin_amdgcn_mfma_f32_16x16x32_f16((a), (b), (c), 0, 0, 0)

// fused GRU combine with t_n = e^{-2 pn}, t_z = e^{-pz}:
// h' = [tn*(h - tz) + (h + tz)] / [(1+tn)(1+tz)]   -- 5 VALU + 1 rcp
__device__ __forceinline__ float gru_combine(float h, float t_n, float t_z) {
    float tz1 = 1.0f + t_z;
    float num = __fmaf_rn(t_n, h - t_z, h + t_z);
    float den = __fmaf_rn(t_n, tz1, tz1);
    return num * __builtin_amdgcn_rcpf(den);
}

// ---------------------------------------------------------------------------
// Pack GRU weights into B-fragment-linear fp16, prescaled:
//   r/z rows x NLOG2E  (MFMA output becomes the exp2 argument directly)
//   n   rows x N2LOG2E
//  f0-1 : Whh0 r     f2-3 : Whh0 z     f4-5 : Whh0 n
//  f6-7 : Wih1 r     f8-9 : Whh1 r
//  f10-11: Wih1 z    f12-13: Whh1 z
//  f14-15: Wih1 n    f16-17: Whh1 n
// packed[((w*18 + f)*512) + lane*8 + j], k = (f&1)*32 + (lane>>4)*8 + j,
// out-row = hb + (lane&15) (+gate offset).
// ---------------------------------------------------------------------------
__global__ void pack_weights_kernel(const float* __restrict__ Whh0,
                                    const float* __restrict__ Wih1,
                                    const float* __restrict__ Whh1,
                                    _Float16* __restrict__ packed)
{
    const int b = blockIdx.x;          // 0..71
    const int w = b / 18, f = b % 18;
    const int l = threadIdx.x;         // 0..63
    const int c = l & 15, g = l >> 4;
    const int hb = w * 16;
    const int kk = f & 1;
    const float* src = Whh0;
    int row = 0;
    float scale = NLOG2E;
    switch (f >> 1) {
        case 0: src = Whh0; row = hb + c;        break;
        case 1: src = Whh0; row = 64 + hb + c;   break;
        case 2: src = Whh0; row = 128 + hb + c;  scale = N2LOG2E; break;
        case 3: src = Wih1; row = hb + c;        break;
        case 4: src = Whh1; row = hb + c;        break;
        case 5: src = Wih1; row = 64 + hb + c;   break;
        case 6: src = Whh1; row = 64 + hb + c;   break;
        case 7: src = Wih1; row = 128 + hb + c;  scale = N2LOG2E; break;
        case 8: src = Whh1; row = 128 + hb + c;  scale = N2LOG2E; break;
    }
    _Float16* dst = packed + ((size_t)(w * 18 + f) * 512) + (size_t)l * 8;
    #pragma unroll
    for (int j = 0; j < 8; ++j) {
        int k = kk * 32 + g * 8 + j;
        dst[j] = (_Float16)(src[row * 64 + k] * scale);
    }
}

// ---------------------------------------------------------------------------
// Layer-specialized MFMA GRU scan (round-10 orientation: A = h from LDS,
// B = weights register-resident; lane owns hid = hb + (l&15), 4 seqs g*4+q).
// Block = 16 sequences, 8 waves (512 threads): waves 0-3 L0, waves 4-7 L1.
// One barrier per phase; xs double-buffered; setprio around MFMA clusters.
// ALL gate biases (prescaled) live in the MFMA C-operand; r/z MFMA outputs
// are exp2-ready.
// ---------------------------------------------------------------------------

#define PHASE_L0(PP, XB, DT)                                                  \
  do {                                                                        \
    const _Float16* h0rd = &h0s[(PP) ^ 1][0][0];                              \
    f16x8 a00 = *(const f16x8*)(h0rd + c * 72 + g * 8);                       \
    f16x8 a01 = *(const f16x8*)(h0rd + c * 72 + 32 + g * 8);                  \
    __builtin_amdgcn_s_setprio(1);                                            \
    f32x4 accr = MFMA16(a01, Br[1], MFMA16(a00, Br[0], vcb0r));               \
    f32x4 accz = MFMA16(a01, Br[3], MFMA16(a00, Br[2], vcb0z));               \
    f32x4 accn = MFMA16(a01, Br[5], MFMA16(a00, Br[4], vb0nh));               \
    __builtin_amdgcn_s_setprio(0);                                            \
    float4 xq = *(const float4*)(&xs_[XB][DT][g * 4]);                        \
    _Pragma("unroll")                                                         \
    for (int q = 0; q < 4; ++q) {                                             \
      int seq = g * 4 + q;                                                    \
      float xv = ((const float*)&xq)[q];                                      \
      float tr = __builtin_amdgcn_exp2f(__fmaf_rn(xv, wr0n, accr[q]));        \
      float r  = __builtin_amdgcn_rcpf(1.0f + tr);                            \
      float tz = __builtin_amdgcn_exp2f(__fmaf_rn(xv, wz0n, accz[q]));        \
      float tn = __builtin_amdgcn_exp2f(                                      \
          __fmaf_rn(r, accn[q], __fmaf_rn(xv, wn0s, b0nxs)));                 \
      float hn = gru_combine(h0st[q], tn, tz);                                \
      h0st[q] = hn;                                                           \
      h0s[PP][seq][hid] = (_Float16)hn;                                       \
    }                                                                         \
  } while (0)

#define PHASE_L1(PP, DOSTORE)                                                 \
  do {                                                                        \
    const _Float16* h0rd = &h0s[(PP) ^ 1][0][0];                              \
    const _Float16* h1rd = &h1s[(PP) ^ 1][0][0];                              \
    f16x8 a00 = *(const f16x8*)(h0rd + c * 72 + g * 8);                       \
    f16x8 a01 = *(const f16x8*)(h0rd + c * 72 + 32 + g * 8);                  \
    f16x8 ah0 = *(const f16x8*)(h1rd + c * 72 + g * 8);                       \
    f16x8 ah1 = *(const f16x8*)(h1rd + c * 72 + 32 + g * 8);                  \
    __builtin_amdgcn_s_setprio(1);                                            \
    f32x4 r1  = MFMA16(ah1, Br[3], MFMA16(ah0, Br[2],                         \
                MFMA16(a01, Br[1], MFMA16(a00, Br[0], vcb1r))));              \
    f32x4 z1  = MFMA16(ah1, Br[7], MFMA16(ah0, Br[6],                         \
                MFMA16(a01, Br[5], MFMA16(a00, Br[4], vcb1z))));              \
    f32x4 xn1 = MFMA16(a01, Br[9],  MFMA16(a00, Br[8],  vb1nx));              \
    f32x4 hn1 = MFMA16(ah1, Br[11], MFMA16(ah0, Br[10], vb1nh));              \
    __builtin_amdgcn_s_setprio(0);                                            \
    _Pragma("unroll")                                                         \
    for (int q = 0; q < 4; ++q) {                                             \
      int seq = g * 4 + q;                                                    \
      float tr = __builtin_amdgcn_exp2f(r1[q]);                               \
      float r  = __builtin_amdgcn_rcpf(1.0f + tr);                            \
      float tz = __builtin_amdgcn_exp2f(z1[q]);                               \
      float tn = __builtin_amdgcn_exp2f(__fmaf_rn(r, hn1[q], xn1[q]));        \
      float hn = gru_combine(h1st[q], tn, tz);                                \
      h1st[q] = hn;                                                           \
      if (DOSTORE) h1s[PP][seq][hid] = (_Float16)hn;                          \
    }                                                                         \
  } while (0)

__global__ __launch_bounds__(512, 4)
void gru_mfma_kernel(const float* __restrict__ x,
                     const _Float16* __restrict__ packedW,
                     const float* __restrict__ Wih0,
                     const float* __restrict__ bih0,
                     const float* __restrict__ bhh0,
                     const float* __restrict__ bih1,
                     const float* __restrict__ bhh1,
                     float* __restrict__ hT_out)
{
    __shared__ __align__(16) _Float16 h0s[2][16][72];   // row stride 144 B
    __shared__ __align__(16) _Float16 h1s[2][16][72];
    __shared__ __align__(16) float xs_[2][32][20];      // double-buffered tiles

    const int tid = threadIdx.x;
    const int l = tid & 63;
    const int w = tid >> 6;          // 0..7
    const bool isL0 = (w < 4);
    const int sl = w & 3;            // hid-slice 0..3
    const int c = l & 15, g = (l >> 4) & 3;
    const int hid = sl * 16 + c;
    const int n0 = blockIdx.x * 16;

    // resident B fragments: L0 waves 6 frags, L1 waves 12 frags
    f16x8 Br[12];
    {
        const f16x8* bp = (const f16x8*)(packedW + (size_t)sl * 18 * 512);
        if (isL0) {
            #pragma unroll
            for (int f = 0; f < 6; ++f) Br[f] = bp[f * 64 + l];
        } else {
            #pragma unroll
            for (int f = 0; f < 12; ++f) Br[f] = bp[(6 + f) * 64 + l];
        }
    }

    // per-lane constants; scalar per lane (lane owns one hid)
    float wr0n = 0.f, wz0n = 0.f, wn0s = 0.f, b0nxs = 0.f;
    float cb0r = 0.f, cb0z = 0.f, b0nh = 0.f;
    float cb1r = 0.f, cb1z = 0.f, b1nx = 0.f, b1nh = 0.f;
    if (isL0) {
        wr0n  = NLOG2E  * Wih0[hid];
        wz0n  = NLOG2E  * Wih0[64 + hid];
        wn0s  = N2LOG2E * Wih0[128 + hid];
        b0nxs = N2LOG2E * bih0[128 + hid];
        cb0r  = NLOG2E  * (bhh0[hid] + bih0[hid]);
        cb0z  = NLOG2E  * (bhh0[64 + hid] + bih0[64 + hid]);
        b0nh  = N2LOG2E * bhh0[128 + hid];
    } else {
        cb1r = NLOG2E  * (bih1[hid] + bhh1[hid]);
        cb1z = NLOG2E  * (bih1[64 + hid] + bhh1[64 + hid]);
        b1nx = N2LOG2E * bih1[128 + hid];
        b1nh = N2LOG2E * bhh1[128 + hid];
    }
    // loop-invariant bias splats for MFMA C-operands
    const f32x4 vcb0r = {cb0r, cb0r, cb0r, cb0r};
    const f32x4 vcb0z = {cb0z, cb0z, cb0z, cb0z};
    const f32x4 vb0nh = {b0nh, b0nh, b0nh, b0nh};
    const f32x4 vcb1r = {cb1r, cb1r, cb1r, cb1r};
    const f32x4 vcb1z = {cb1z, cb1z, cb1z, cb1z};
    const f32x4 vb1nx = {b1nx, b1nx, b1nx, b1nx};
    const f32x4 vb1nh = {b1nh, b1nh, b1nh, b1nh};

    for (int p = tid; p < 2 * 16 * 72; p += 512) {
        (&h0s[0][0][0])[p] = (_Float16)0.0f;
        (&h1s[0][0][0])[p] = (_Float16)0.0f;
    }
    float h0st[4] = {0.f, 0.f, 0.f, 0.f};
    float h1st[4] = {0.f, 0.f, 0.f, 0.f};

    auto stage_x = [&](int t0) {
        int buf = (t0 >> 5) & 1;
        int tb = tid & 31;          // timestep within tile
        int ss = tid >> 5;          // 0..15 sequence
        xs_[buf][tb][ss] = x[(size_t)(n0 + ss) * T_ + t0 + tb];
    };

    // prologue: phase 0 (L0 only), parity 0, buffer 0
    stage_x(0);
    __syncthreads();
    if (isL0) PHASE_L0(0, 0, 0);

    // main loop: phases 1..510 in parity-static pairs (odd, even).
    for (int p = 1; p < T_ - 1; p += 2) {
        __syncthreads();
        if (isL0) PHASE_L0(1, (p >> 5) & 1, p & 31); else PHASE_L1(1, true);
        if ((p & 31) == 31) stage_x(p + 1);
        __syncthreads();
        if (isL0) PHASE_L0(0, ((p + 1) >> 5) & 1, (p + 1) & 31);
        else      PHASE_L1(0, true);
    }

    // leftover phase 511 (parity 1, buffer 1, row 31)
    __syncthreads();
    if (isL0) PHASE_L0(1, 1, 31); else PHASE_L1(1, true);

    // epilogue: phase 512 (L1 only), parity 0
    __syncthreads();
    if (!isL0) {
        PHASE_L1(0, false);
        #pragma unroll
        for (int q = 0; q < 4; ++q) {
            int seq = g * 4 + q;
            hT_out[(size_t)(n0 + seq) * H_ + hid] = h1st[q];
        }
    }
}

// ---------------------------------------------------------------------------
// Heads: mu, softplus(d), v (R=32), resid = y - mu. One thread per sequence.
// ---------------------------------------------------------------------------
__global__ __launch_bounds__(256)
void heads_kernel(const float* __restrict__ hT,
                  const float* __restrict__ y,
                  const float* __restrict__ Wm, const float* __restrict__ bm,
                  const float* __restrict__ Wd, const float* __restrict__ bd,
                  const float* __restrict__ Wv, const float* __restrict__ bv,
                  float* __restrict__ v_out,
                  float* __restrict__ dd_out,
                  float* __restrict__ r_out)
{
    const int n = blockIdx.x * 256 + threadIdx.x;
    const float* h = hT + (size_t)n * H_;

    float hreg[H_];
    #pragma unroll
    for (int j = 0; j < H_; j += 4) {
        float4 q = *(const float4*)(h + j);
        hreg[j] = q.x; hreg[j + 1] = q.y; hreg[j + 2] = q.z; hreg[j + 3] = q.w;
    }
    float mu = bm[0], dv = bd[0];
    #pragma unroll
    for (int j = 0; j < H_; ++j) {
        mu = __fmaf_rn(Wm[j], hreg[j], mu);
        dv = __fmaf_rn(Wd[j], hreg[j], dv);
    }
    r_out[n]  = y[n] - mu;
    dd_out[n] = log1pf(__expf(dv));   // softplus

    for (int k = 0; k < R_; ++k) {
        float acc = bv[k];
        #pragma unroll
        for (int j = 0; j < H_; ++j)
            acc = __fmaf_rn(Wv[k * H_ + j], hreg[j], acc);
        v_out[(size_t)n * R_ + k] = acc;
    }
}

__device__ __forceinline__ float block_reduce_sum256(float* red, int tid, float val)
{
    red[tid] = val;
    __syncthreads();
    for (int off = 128; off > 0; off >>= 1) {
        if (tid < off) red[tid] += red[tid + off];
        __syncthreads();
    }
    float r = red[0];
    __syncthreads();
    return r;
}

// ---------------------------------------------------------------------------
// Per-batch Woodbury: sigma = V V^T + D.
// quad  = r^T D^-1 r - u^T M^-1 u,  u = V^T D^-1 r,  M = I + V^T D^-1 V
// logdet= sum log d + logdet M  (32x32 Cholesky)
// ---------------------------------------------------------------------------
__global__ __launch_bounds__(256)
void woodbury_kernel(const float* __restrict__ v_in,
                     const float* __restrict__ dd_in,
                     const float* __restrict__ r_in,
                     float* __restrict__ batch_out)
{
    __shared__ float Vl[C_][R_ + 1];
    __shared__ float Vw[C_][R_ + 1];
    __shared__ float wi[C_];
    __shared__ float rl[C_];
    __shared__ float red[256];
    __shared__ float MA[R_][R_ + 1];
    __shared__ float uA[R_], yA[R_], wA[R_];

    const int tid = threadIdx.x;
    const int nb  = blockIdx.x * C_;

    for (int p = tid; p < C_ * R_; p += 256) {
        int cc = p >> 5, k = p & 31;
        Vl[cc][k] = v_in[(size_t)(nb + cc) * R_ + k];
    }
    float dval = dd_in[nb + tid];
    float winv = 1.0f / dval;
    float rv   = r_in[nb + tid];
    wi[tid] = winv;
    rl[tid] = rv;
    __syncthreads();

    for (int p = tid; p < C_ * R_; p += 256) {
        int cc = p >> 5, k = p & 31;
        Vw[cc][k] = Vl[cc][k] * wi[cc];
    }
    __syncthreads();

    float slogd = block_reduce_sum256(red, tid, __logf(dval));
    float rDr   = block_reduce_sum256(red, tid, rv * rv * winv);

    #pragma unroll
    for (int e = 0; e < 4; ++e) {
        int p = tid + e * 256;
        int i = p >> 5, j = p & 31;
        float acc = (i == j) ? 1.0f : 0.0f;
        for (int cc = 0; cc < C_; ++cc)
            acc = __fmaf_rn(Vw[cc][i], Vl[cc][j], acc);
        MA[i][j] = acc;
    }
    if (tid < R_) {
        float acc = 0.0f;
        for (int cc = 0; cc < C_; ++cc)
            acc = __fmaf_rn(Vw[cc][tid], rl[cc], acc);
        uA[tid] = acc;
    }
    __syncthreads();

    for (int k = 0; k < R_; ++k) {
        if (tid == 0) MA[k][k] = sqrtf(MA[k][k]);
        __syncthreads();
        if (tid > k && tid < R_) MA[tid][k] /= MA[k][k];
        __syncthreads();
        if (tid > k && tid < R_) {
            float ljk = MA[tid][k];
            for (int i2 = k + 1; i2 <= tid; ++i2)
                MA[tid][i2] -= ljk * MA[i2][k];
        }
        __syncthreads();
    }
    float ldm = block_reduce_sum256(red, tid,
                    (tid < R_) ? 2.0f * __logf(MA[tid][tid]) : 0.0f);

    if (tid == 0) {
        for (int k = 0; k < R_; ++k) {
            float sv = uA[k];
            for (int i2 = 0; i2 < k; ++i2) sv -= MA[k][i2] * yA[i2];
            yA[k] = sv / MA[k][k];
        }
        for (int k = R_ - 1; k >= 0; --k) {
            float sv = yA[k];
            for (int i2 = k + 1; i2 < R_; ++i2) sv -= MA[i2][k] * wA[i2];
            wA[k] = sv / MA[k][k];
        }
        float uw = 0.0f;
        for (int k = 0; k < R_; ++k) uw += wA[k] * uA[k];
        batch_out[blockIdx.x] = (rDr - uw) + slogd + ldm;
    }
}

__global__ void finalize_kernel(const float* __restrict__ bws, float* __restrict__ out)
{
    float v = bws[threadIdx.x];
    #pragma unroll
    for (int off = 32; off > 0; off >>= 1)
        v += __shfl_down(v, off, 64);
    if (threadIdx.x == 0) out[0] = v * (1.0f / 64.0f);
}

} // anonymous namespace

extern "C" void kernel_launch(void* const* d_in, const int* in_sizes, int n_in,
                              void* d_out, int out_size, void* d_ws, size_t ws_size,
                              hipStream_t stream)
{
    const float* x    = (const float*)d_in[0];
    const float* y    = (const float*)d_in[1];
    const float* Wih0 = (const float*)d_in[2];
    const float* Whh0 = (const float*)d_in[3];
    const float* bih0 = (const float*)d_in[4];
    const float* bhh0 = (const float*)d_in[5];
    const float* Wih1 = (const float*)d_in[6];
    const float* Whh1 = (const float*)d_in[7];
    const float* bih1 = (const float*)d_in[8];
    const float* bhh1 = (const float*)d_in[9];
    const float* Wm   = (const float*)d_in[10];
    const float* bm   = (const float*)d_in[11];
    const float* Wd   = (const float*)d_in[12];
    const float* bd   = (const float*)d_in[13];
    const float* Wv   = (const float*)d_in[14];
    const float* bv   = (const float*)d_in[15];

    char* ws = (char*)d_ws;
    float*    hT     = (float*)(ws + 0);                 // N*64 f32   (4 MB)
    float*    v_ws   = (float*)(ws + 4194304);           // N*32 f32   (2 MB)
    float*    dd_ws  = (float*)(ws + 6291456);           // N f32
    float*    r_ws   = (float*)(ws + 6356992);           // N f32
    float*    b_ws   = (float*)(ws + 6422528);           // B f32
    _Float16* packed = (_Float16*)(ws + 6423552);        // 4*18*512 fp16 (73728 B)

    pack_weights_kernel<<<72, 64, 0, stream>>>(Whh0, Wih1, Whh1, packed);
    gru_mfma_kernel<<<N_ / 16, 512, 0, stream>>>(
        x, packed, Wih0, bih0, bhh0, bih1, bhh1, hT);
    heads_kernel<<<N_ / 256, 256, 0, stream>>>(
        hT, y, Wm, bm, Wd, bd, Wv, bv, v_ws, dd_ws, r_ws);
    woodbury_kernel<<<B_, 256, 0, stream>>>(v_ws, dd_ws, r_ws, b_ws);
    finalize_kernel<<<1, 64, 0, stream>>>(b_ws, (float*)d_out);
}